// Round 1
// baseline (467.371 us; speedup 1.0000x reference)
//
#include <hip/hip_runtime.h>
#include <hip/hip_bf16.h>

// Shifted-window attention, b=1, h=w=256, c=128, ns=8 -> 64 windows of 1024 tokens.
// Key simplification: the reference rolls axes (w, c); the c-roll cancels exactly,
// the w-roll is a +16 (mod 256) column gather, and output scatter == input gather.

typedef __attribute__((ext_vector_type(8))) short bhalf8;   // 8 x bf16
typedef __attribute__((ext_vector_type(4))) float f4;
typedef __attribute__((ext_vector_type(4))) int i4;

#define MFMA16(a, b, c) __builtin_amdgcn_mfma_f32_16x16x32_bf16((a), (b), (c), 0, 0, 0)

__device__ __forceinline__ unsigned short f2bf(float f) {
    unsigned u = __builtin_bit_cast(unsigned, f);
    return (unsigned short)((u + 0x7fffu + ((u >> 16) & 1u)) >> 16);  // RNE
}

// global element offset of window-row r (0..1023) for window (i,j); channel 0
__device__ __forceinline__ int rowOff(int i, int j, int r) {
    int y = i * 32 + (r >> 5);
    int x = (j * 32 + (r & 31) + 16) & 255;   // the surviving W-roll
    return ((y << 8) + x) << 7;               // *(C=128)
}

__global__ __launch_bounds__(256, 2)
void swin_attn_kernel(const float* __restrict__ Qg, const float* __restrict__ Kg,
                      const float* __restrict__ Vg, const float* __restrict__ Mg,
                      float* __restrict__ Og) {
    // LDS: [0,32K) Q-stage (prologue) -> K tile [0,16K) + Vt tile [16K,32K) (main loop)
    //      [32K,48K) per-wave P buffers (4 KB each)
    __shared__ __align__(16) unsigned char smem[49152];

    const int tid  = threadIdx.x;
    const int lane = tid & 63;
    const int wv   = tid >> 6;          // wave 0..3
    const int l15  = lane & 15;
    const int l4   = lane >> 4;         // 0..3

    // XCD swizzle: all 8 q-tiles of a window land on the same XCD (g%8 const per window)
    const int g     = blockIdx.x;
    const int w_idx = (g & 7) + ((g >> 6) << 3);   // window 0..63
    const int tq    = (g >> 3) & 7;                // q-tile 0..7
    const int wi = w_idx >> 3, wj = w_idx & 7;
    const int q0 = tq * 128;

    const float SCALE = 11.313708498984760f;               // sqrt(128)
    const float K1    = 1.4426950408889634f / SCALE;       // log2(e)/sqrt(128)

    // ---------------- stage Q tile (128 rows x 128 ch, bf16, XOR-swizzled) -------------
    {
        const int rl  = tid >> 4;
        const int ch0 = (tid & 15) * 8;
#pragma unroll
        for (int p = 0; p < 8; ++p) {
            int row = p * 16 + rl;
            const float* src = Qg + rowOff(wi, wj, q0 + row) + ch0;
            f4 a = *(const f4*)src;
            f4 b = *(const f4*)(src + 4);
            union { unsigned short us[8]; i4 v; } pk;
#pragma unroll
            for (int u = 0; u < 4; ++u) { pk.us[u] = f2bf(a[u]); pk.us[u + 4] = f2bf(b[u]); }
            *(i4*)(smem + row * 256 + ((ch0 * 2) ^ ((row & 7) << 4))) = pk.v;
        }
    }
    __syncthreads();

    // Q fragments to registers: wave wv owns q rows [wv*32, wv*32+32)
    bhalf8 qf[2][4];
#pragma unroll
    for (int qb = 0; qb < 2; ++qb)
#pragma unroll
        for (int ks = 0; ks < 4; ++ks) {
            int row = wv * 32 + qb * 16 + l15;
            qf[qb][ks] = *(const bhalf8*)(smem + row * 256 + ((ks * 64 + l4 * 16) ^ ((row & 7) << 4)));
        }
    __syncthreads();

    f4 Oacc[2][8];
#pragma unroll
    for (int qb = 0; qb < 2; ++qb)
#pragma unroll
        for (int cf = 0; cf < 8; ++cf) Oacc[qb][cf] = (f4){0.f, 0.f, 0.f, 0.f};
    float lpart[8] = {0.f, 0.f, 0.f, 0.f, 0.f, 0.f, 0.f, 0.f};

    unsigned char* Plds = smem + 32768 + wv * 4096;        // [32 q][64 s] bf16, swizzled
    const float* mrow = Mg + ((size_t)w_idx << 20);        // mask[w] (1024x1024)

    for (int kv = 0; kv < 16; ++kv) {
        const int s0 = kv * 64;

        // ---- mask -> MFMA C-init (mask*sqrt(128)); issued first to hide HBM latency ----
        f4 acc[2][4];
#pragma unroll
        for (int qb = 0; qb < 2; ++qb)
#pragma unroll
            for (int sf = 0; sf < 4; ++sf) {
                int qrow = q0 + wv * 32 + qb * 16 + l4 * 4;
                const float* mp = mrow + (size_t)qrow * 1024 + (s0 + sf * 16 + l15);
                f4 t;
                t[0] = mp[0] * SCALE; t[1] = mp[1024] * SCALE;
                t[2] = mp[2048] * SCALE; t[3] = mp[3072] * SCALE;
                acc[qb][sf] = t;
            }

        // ---------------- stage K tile (64x128) and Vt tile (128x64) ----------------
        {
            const int rl  = tid >> 4;
            const int ch0 = (tid & 15) * 8;
#pragma unroll
            for (int p = 0; p < 4; ++p) {
                int row = p * 16 + rl;
                const float* src = Kg + rowOff(wi, wj, s0 + row) + ch0;
                f4 a = *(const f4*)src;
                f4 b = *(const f4*)(src + 4);
                union { unsigned short us[8]; i4 v; } pk;
#pragma unroll
                for (int u = 0; u < 4; ++u) { pk.us[u] = f2bf(a[u]); pk.us[u + 4] = f2bf(b[u]); }
                *(i4*)(smem + row * 256 + ((ch0 * 2) ^ ((row & 7) << 4))) = pk.v;
            }
            // V transposed at stage: thread grabs 8 consecutive s for one channel
            // (64B-coalesced per 16-lane group), writes one b128 row-chunk of Vt.
#pragma unroll
            for (int p = 0; p < 4; ++p) {
                int task = tid + p * 256;
                int ch = task & 127;
                int sb = task >> 7;                       // 0..7 -> s0l = sb*8
                union { unsigned short us[8]; i4 v; } pk;
#pragma unroll
                for (int u = 0; u < 8; ++u)
                    pk.us[u] = f2bf(Vg[rowOff(wi, wj, s0 + sb * 8 + u) + ch]);
                *(i4*)(smem + 16384 + ch * 128 + ((sb * 16) ^ ((ch & 7) << 4))) = pk.v;
            }
        }
        __syncthreads();

        // ---------------- S = Q K^T / sqrt(c) + mask  (in exp2 domain later) ---------
#pragma unroll
        for (int sf = 0; sf < 4; ++sf) {
            int row = sf * 16 + l15;
            const unsigned char* rb = smem + row * 256;
#pragma unroll
            for (int ks = 0; ks < 4; ++ks) {
                bhalf8 kb = *(const bhalf8*)(rb + ((ks * 64 + l4 * 16) ^ ((row & 7) << 4)));
                acc[0][sf] = MFMA16(qf[0][ks], kb, acc[0][sf]);
                acc[1][sf] = MFMA16(qf[1][ks], kb, acc[1][sf]);
            }
        }

        // ---------------- p = exp(S) (no max-sub; scores bounded), write P ----------
#pragma unroll
        for (int qb = 0; qb < 2; ++qb)
#pragma unroll
            for (int sf = 0; sf < 4; ++sf)
#pragma unroll
                for (int r = 0; r < 4; ++r) {
                    float p = __builtin_amdgcn_exp2f(acc[qb][sf][r] * K1);
                    lpart[qb * 4 + r] += p;
                    int q = qb * 16 + l4 * 4 + r;
                    int s = sf * 16 + l15;
                    *(unsigned short*)(Plds + q * 128 + ((s * 2) ^ ((q & 7) << 4))) = f2bf(p);
                }

        // ---------------- O += P V ---------------------------------------------------
        bhalf8 pa[2][2];
#pragma unroll
        for (int qb = 0; qb < 2; ++qb)
#pragma unroll
            for (int ks = 0; ks < 2; ++ks) {
                int q = qb * 16 + l15;
                pa[qb][ks] = *(const bhalf8*)(Plds + q * 128 + ((ks * 64 + l4 * 16) ^ ((q & 7) << 4)));
            }
#pragma unroll
        for (int cf = 0; cf < 8; ++cf) {
            int row = cf * 16 + l15;
            const unsigned char* rb = smem + 16384 + row * 128;
#pragma unroll
            for (int ks = 0; ks < 2; ++ks) {
                bhalf8 vb = *(const bhalf8*)(rb + ((ks * 64 + l4 * 16) ^ ((row & 7) << 4)));
                Oacc[0][cf] = MFMA16(pa[0][ks], vb, Oacc[0][cf]);
                Oacc[1][cf] = MFMA16(pa[1][ks], vb, Oacc[1][cf]);
            }
        }
        __syncthreads();
    }

    // row sums: reduce partials across the 16 lanes of each group (xor 1,2,4,8)
#pragma unroll
    for (int t = 0; t < 8; ++t) {
        float v = lpart[t];
        v += __shfl_xor(v, 1); v += __shfl_xor(v, 2);
        v += __shfl_xor(v, 4); v += __shfl_xor(v, 8);
        lpart[t] = 1.0f / v;
    }

    // write out (scatter address == gather address; 64B-coalesced per 16-lane group)
#pragma unroll
    for (int qb = 0; qb < 2; ++qb)
#pragma unroll
        for (int r = 0; r < 4; ++r) {
            int rg = q0 + wv * 32 + qb * 16 + l4 * 4 + r;
            float* dst = Og + rowOff(wi, wj, rg);
            float rin = lpart[qb * 4 + r];
#pragma unroll
            for (int cf = 0; cf < 8; ++cf)
                dst[cf * 16 + l15] = Oacc[qb][cf][r] * rin;
        }
}

extern "C" void kernel_launch(void* const* d_in, const int* in_sizes, int n_in,
                              void* d_out, int out_size, void* d_ws, size_t ws_size,
                              hipStream_t stream) {
    const float* q = (const float*)d_in[0];
    const float* k = (const float*)d_in[1];
    const float* v = (const float*)d_in[2];
    const float* m = (const float*)d_in[3];
    float* out = (float*)d_out;
    hipLaunchKernelGGL(swin_attn_kernel, dim3(512), dim3(256), 0, stream, q, k, v, m, out);
}